// Round 3
// baseline (138.486 us; speedup 1.0000x reference)
//
#include <hip/hip_runtime.h>
#include <hip/hip_bf16.h>

// Problem: N=2, L=8192, dim=256, H=8, Pd=32. seg = n*8+h (16 segs).
// Pipeline:
//  K1 k_fused : per 64-row tile, MFMA q (phi) / v / k (phi); c,cden in-register
//               (pq, v never hit HBM); per-tile totals; pk stored bf16.
//  K2 k_off   : exclusive prefix of 128 tile-totals per seg (64 slots).
//  K3 k_scan  : per 64-row tile per wave: offset + serial scan, num/den via
//               LDS batch, coalesced float4 out.
// ws (float units): pk[bf16 16*8192*32] = 2097152 | c 131072 | cden 131072 |
//                   tot 16*128*64 = 131072 | off 131072   (~10.4 MB)

typedef __attribute__((ext_vector_type(8))) short short8;  // 8 bf16
typedef __attribute__((ext_vector_type(4))) float f32x4;

__device__ __forceinline__ float phi_f(float x) {
    return x > 0.f ? x + 1.f : __expf(x);   // elu(x)+1
}
__device__ __forceinline__ unsigned short f2bf(float x) {
    __hip_bfloat16 h = __float2bfloat16(x);   // RNE
    return *reinterpret_cast<unsigned short*>(&h);
}
__device__ __forceinline__ float bf2f(unsigned short u) {
    unsigned int v = ((unsigned int)u) << 16;
    return __uint_as_float(v);
}

// ---------------- K1: fused qkv GEMM + coef + totals + pk store ----------
// grid 256 (one 64-row tile / block), block 512 (8 waves; wave w = head w,
// cols w*32..w*32+31). VGPR-heavy; 1 block/CU by grid anyway.
__global__ __launch_bounds__(512, 1) void k_fused(
        const float* __restrict__ Y, const float* __restrict__ X,
        const float* __restrict__ Wq, const float* __restrict__ Wk,
        const float* __restrict__ Wv,
        unsigned short* __restrict__ pk_out,
        float* __restrict__ c_out, float* __restrict__ cd_out,
        float* __restrict__ tot)
{
    __shared__ float scc[64][8];          // c per (row, head)
    __shared__ float scd[64][8];
    __shared__ float spqprev[256];        // pq of row mbase-1 (0 at seg start)
    __shared__ float yrow[256];
    __shared__ __align__(16) unsigned short U[16896];  // 33792 B union
    unsigned short* As = U;               // 64  x 40
    unsigned short* Bs = U + 2560;        // 256 x 40
    unsigned short* spkout = U;           // 64  x 264 (pk staging for store)

    const int bx = blockIdx.x;
    const int mbase = bx * 64;
    const int n = mbase >> 13;
    const int lseg0 = mbase & 8191;
    const int tileinseg = lseg0 >> 6;
    const int t = threadIdx.x;
    const int w  = t >> 6;                // wave = head
    const int lane = t & 63;
    const int ln = lane & 15;
    const int qd = lane >> 4;

    // one GEMM pass: out = src @ W^T for this block's 64 rows, 256 cols
    auto gemm_pass = [&](const float* src, const float* W, f32x4 (&acc)[4][2]) {
#pragma unroll
        for (int i = 0; i < 4; i++)
#pragma unroll
            for (int j = 0; j < 2; j++) acc[i][j] = (f32x4){0.f, 0.f, 0.f, 0.f};
        for (int kt = 0; kt < 8; kt++) {
            const int k0 = kt * 32;
            {   // A: 64x32, 512 float4 chunks, 1/thread
                const int row = t >> 3, q = t & 7;
                float4 f = *(const float4*)(src + (size_t)(mbase + row) * 256 + k0 + q * 4);
                ushort4 h;
                h.x = f2bf(f.x); h.y = f2bf(f.y); h.z = f2bf(f.z); h.w = f2bf(f.w);
                *(ushort4*)&As[row * 40 + q * 4] = h;
            }
#pragma unroll
            for (int i2 = 0; i2 < 4; i2++) {  // B: 256x32, 2048 chunks, 4/thread
                const int idx = t + 512 * i2;
                const int row = idx >> 3, q = idx & 7;
                float4 f = *(const float4*)(W + (size_t)row * 256 + k0 + q * 4);
                ushort4 h;
                h.x = f2bf(f.x); h.y = f2bf(f.y); h.z = f2bf(f.z); h.w = f2bf(f.w);
                *(ushort4*)&Bs[row * 40 + q * 4] = h;
            }
            __syncthreads();
            short8 a[4], b[2];
#pragma unroll
            for (int i = 0; i < 4; i++)
                a[i] = *(const short8*)&As[(i * 16 + ln) * 40 + qd * 8];
#pragma unroll
            for (int j = 0; j < 2; j++)
                b[j] = *(const short8*)&Bs[(w * 32 + j * 16 + ln) * 40 + qd * 8];
#pragma unroll
            for (int i = 0; i < 4; i++)
#pragma unroll
                for (int j = 0; j < 2; j++)
                    acc[i][j] = __builtin_amdgcn_mfma_f32_16x16x32_bf16(a[i], b[j], acc[i][j], 0, 0, 0);
            __syncthreads();
        }
    };

    f32x4 aq[4][2], av[4][2];

    // ---- pass 1: pq = phi(Y @ Wq^T) ----
    gemm_pass(Y, Wq, aq);
#pragma unroll
    for (int i = 0; i < 4; i++)
#pragma unroll
        for (int j = 0; j < 2; j++)
#pragma unroll
            for (int r = 0; r < 4; r++) aq[i][j][r] = phi_f(aq[i][j][r]);

    // ---- boundary row pq[mbase-1] (exact fp32 dot; 0 at segment start) ----
    if (lseg0 == 0) {
        if (t < 256) spqprev[t] = 0.f;
    } else {
        if (t < 64) *(float4*)&yrow[t * 4] = *(const float4*)(Y + (size_t)(mbase - 1) * 256 + t * 4);
        __syncthreads();
        if (t < 256) {
            const float* wr = Wq + (size_t)t * 256;
            float s = 0.f;
#pragma unroll 8
            for (int k = 0; k < 256; k += 4) {
                float4 ww = *(const float4*)(wr + k);
                s += yrow[k] * ww.x + yrow[k + 1] * ww.y + yrow[k + 2] * ww.z + yrow[k + 3] * ww.w;
            }
            spqprev[t] = phi_f(s);
        }
    }
    __syncthreads();

    // ---- pass 2: v = X @ Wv^T ----
    gemm_pass(X, Wv, av);

    // ---- c, cden per (row, head): dpq chain via shuffles ----
    float ccr[4][4], cdr[4][4];
#pragma unroll
    for (int i = 0; i < 4; i++)
#pragma unroll
        for (int r = 0; r < 4; r++) { ccr[i][r] = 0.f; cdr[i][r] = 0.f; }
#pragma unroll
    for (int j = 0; j < 2; j++) {
        float carry = spqprev[w * 32 + j * 16 + ln];
#pragma unroll
        for (int i = 0; i < 4; i++) {
            const float p0 = aq[i][j][0], p1 = aq[i][j][1], p2 = aq[i][j][2], p3 = aq[i][j][3];
            const float up3 = __shfl_up(p3, 16);
            const float prev0 = (qd == 0) ? carry : up3;
            const float d0 = p0 - prev0, d1 = p1 - p0, d2 = p2 - p1, d3 = p3 - p2;
            ccr[i][0] += d0 * av[i][j][0]; cdr[i][0] += d0;
            ccr[i][1] += d1 * av[i][j][1]; cdr[i][1] += d1;
            ccr[i][2] += d2 * av[i][j][2]; cdr[i][2] += d2;
            ccr[i][3] += d3 * av[i][j][3]; cdr[i][3] += d3;
            carry = __shfl(p3, ln + 48);   // row i*16+15 value, any qd
        }
    }
#pragma unroll
    for (int i = 0; i < 4; i++)
#pragma unroll
        for (int r = 0; r < 4; r++) {
            float x = ccr[i][r];
            x += __shfl_xor(x, 1); x += __shfl_xor(x, 2);
            x += __shfl_xor(x, 4); x += __shfl_xor(x, 8);
            float y = cdr[i][r];
            y += __shfl_xor(y, 1); y += __shfl_xor(y, 2);
            y += __shfl_xor(y, 4); y += __shfl_xor(y, 8);
            if (ln == 0) { scc[i * 16 + qd * 4 + r][w] = x; scd[i * 16 + qd * 4 + r][w] = y; }
        }
    __syncthreads();

    // ---- c/cden to global ----
    {
        const int hh = t >> 6, row = t & 63;
        const size_t gi = ((size_t)(n * 8 + hh)) * 8192 + lseg0 + row;
        c_out[gi]  = scc[row][hh];
        cd_out[gi] = scd[row][hh];
    }

    // ---- pass 3: pk = phi(X @ Wk^T) (reuse aq) ----
    gemm_pass(X, Wk, aq);
#pragma unroll
    for (int i = 0; i < 4; i++)
#pragma unroll
        for (int j = 0; j < 2; j++)
#pragma unroll
            for (int r = 0; r < 4; r++) aq[i][j][r] = phi_f(aq[i][j][r]);

    // ---- per-tile totals: sum_rows coef * pk per col ----
#pragma unroll
    for (int j = 0; j < 2; j++) {
        float tn = 0.f, td = 0.f;
#pragma unroll
        for (int i = 0; i < 4; i++)
#pragma unroll
            for (int r = 0; r < 4; r++) {
                const int row = i * 16 + qd * 4 + r;
                const float pv = aq[i][j][r];
                tn += scc[row][w] * pv;
                td += scd[row][w] * pv;
            }
        tn += __shfl_xor(tn, 16); tn += __shfl_xor(tn, 32);
        td += __shfl_xor(td, 16); td += __shfl_xor(td, 32);
        if (qd == 0) {
            const int d = j * 16 + ln;
            const size_t bidx = ((size_t)(n * 8 + w) * 128 + tileinseg) * 64;
            tot[bidx + d]      = tn;
            tot[bidx + 32 + d] = td;
        }
    }

    // ---- pk to global (bf16), via LDS transpose for coalescing ----
    // Last gemm_pass ended with a barrier; totals phase didn't touch U.
#pragma unroll
    for (int j = 0; j < 2; j++)
#pragma unroll
        for (int i = 0; i < 4; i++)
#pragma unroll
            for (int r = 0; r < 4; r++)
                spkout[(i * 16 + qd * 4 + r) * 264 + w * 32 + j * 16 + ln] = f2bf(aq[i][j][r]);
    __syncthreads();
#pragma unroll
    for (int it = 0; it < 4; it++) {
        const int idx = t + 512 * it;      // 0..2047 (64 rows x 32 col-groups)
        const int row = idx >> 5, cg = idx & 31;
        short8 vals = *(const short8*)&spkout[row * 264 + cg * 8];
        const int col8 = cg * 8, hh = col8 >> 5, d8 = col8 & 31;
        const size_t ga = (((size_t)(n * 8 + hh)) * 8192 + lseg0 + row) * 32 + d8;
        *(short8*)(pk_out + ga) = vals;
    }
}

// ---------------- K2: exclusive prefix over 128 tile-totals / seg ---------
// grid 16, block 256 (wave wv -> tiles wv*32..+31).
__global__ __launch_bounds__(256) void k_off(
        const float* __restrict__ tot, float* __restrict__ offs)
{
    __shared__ float wsum[4][64];
    const int seg = blockIdx.x, t = threadIdx.x;
    const int wv = t >> 6, lane = t & 63;
    float s = 0.f;
#pragma unroll
    for (int ch = 0; ch < 32; ch++)
        s += tot[((size_t)seg * 128 + wv * 32 + ch) * 64 + lane];
    wsum[wv][lane] = s;
    __syncthreads();
    float run = 0.f;
    for (int j = 0; j < wv; j++) run += wsum[j][lane];
#pragma unroll
    for (int ch = 0; ch < 32; ch++) {
        const size_t idx = ((size_t)seg * 128 + wv * 32 + ch) * 64 + lane;
        offs[idx] = run;
        run += tot[idx];
    }
}

// ---------------- K3: final scan + divide + coalesced store ---------------
// grid 512 = 16 segs x 32 blocks (256 rows). Wave wv owns tile wv (64 rows).
__global__ __launch_bounds__(256) void k_scan(
        const unsigned short* __restrict__ pk, const float* __restrict__ c,
        const float* __restrict__ cd, const float* __restrict__ offs,
        float* __restrict__ out)
{
    __shared__ float spk[256 * 32];        // 32 KB
    __shared__ float sc[256], sd[256];
    __shared__ float ob[4][2][16][32];     // 16 KB num/den batch

    const int bx = blockIdx.x;
    const int seg = bx >> 5, blk = bx & 31;
    const int n = seg >> 3, h = seg & 7;
    const int t = threadIdx.x;
    const int l0 = blk * 256;

#pragma unroll
    for (int i = 0; i < 4; i++) {          // stage pk -> fp32 LDS
        const int idx = t + 256 * i;       // 1024 chunks of 8 bf16
        const int row = idx >> 2, c8 = idx & 3;
        short8 vv = *(const short8*)(pk + ((size_t)seg * 8192 + l0 + row) * 32 + c8 * 8);
        float* dstp = &spk[row * 32 + c8 * 8];
#pragma unroll
        for (int e = 0; e < 8; e++) dstp[e] = bf2f((unsigned short)vv[e]);
    }
    sc[t] = c[(size_t)seg * 8192 + l0 + t];
    sd[t] = cd[(size_t)seg * 8192 + l0 + t];
    __syncthreads();

    const int wv = t >> 6, lane = t & 63;
    const int d = lane & 31, part = lane >> 5;
    float run = offs[((size_t)seg * 128 + blk * 4 + wv) * 64 + lane];
    const float* coefs = part ? sd : sc;

    for (int mb = 0; mb < 4; mb++) {
#pragma unroll
        for (int p = 0; p < 16; p++) {
            const int m = wv * 64 + mb * 16 + p;
            run += coefs[m] * spk[m * 32 + d];
            ob[wv][part][p][d] = run;
        }
        __syncthreads();
#pragma unroll
        for (int it = 0; it < 2; it++) {
            const int fl = t + 256 * it;   // 512 float4s per batch
            const int wv2 = fl >> 7, rem = fl & 127, p = rem >> 3, d4 = rem & 7;
            float4 nu = *(const float4*)&ob[wv2][0][p][d4 * 4];
            float4 de = *(const float4*)&ob[wv2][1][p][d4 * 4];
            float4 o4 = make_float4(nu.x / de.x, nu.y / de.y, nu.z / de.z, nu.w / de.w);
            const int l = l0 + wv2 * 64 + mb * 16 + p;
            *(float4*)(out + ((size_t)n * 8192 + l) * 256 + h * 32 + d4 * 4) = o4;
        }
        __syncthreads();
    }
}

extern "C" void kernel_launch(void* const* d_in, const int* in_sizes, int n_in,
                              void* d_out, int out_size, void* d_ws, size_t ws_size,
                              hipStream_t stream)
{
    const float* Y  = (const float*)d_in[0];
    const float* X  = (const float*)d_in[1];
    const float* Wq = (const float*)d_in[2];
    const float* Wk = (const float*)d_in[3];
    const float* Wv = (const float*)d_in[4];
    float* out = (float*)d_out;

    float* ws = (float*)d_ws;
    unsigned short* pk = (unsigned short*)ws;     // 4194304 bf16 = 2097152 floats
    float* c   = ws + 2097152;
    float* cd  = c  + 131072;
    float* tot = cd + 131072;
    float* off = tot + 131072;

    hipLaunchKernelGGL(k_fused, dim3(256), dim3(512), 0, stream,
                       Y, X, Wq, Wk, Wv, pk, c, cd, tot);
    hipLaunchKernelGGL(k_off,   dim3(16),  dim3(256), 0, stream, tot, off);
    hipLaunchKernelGGL(k_scan,  dim3(512), dim3(256), 0, stream, pk, c, cd, off, out);
}

// Round 4
// 132.628 us; speedup vs baseline: 1.0442x; 1.0442x over previous
//
#include <hip/hip_runtime.h>
#include <hip/hip_bf16.h>

// N=2, L=8192, dim=256, H=8, Pd=32. seg = n*8+h (16 segs of 8192).
// K1 k_prep : fp32 -> bf16, permuted to MFMA fragment order
//             [tile16][kt(8)][qd(4)][ln(16)][e(8)] so one coalesced 16B/lane
//             global load = one MFMA A/B fragment. Y, X, and Wq/Wv/Wk.
// K2 k_gemm : register-resident fused GEMM (no LDS staging, no k-loop
//             barriers). 32 rows/block, 4 waves (wave = 64 cols = 2 heads).
//             q/v/k + boundary-q MFMA'd together; c,cden via shuffles;
//             32-row tile totals; pk stored bf16.
// K3 k_off  : exclusive prefix of 256 tile-totals per seg (64 slots).
// K4 k_scan : serial scan per wave (64 rows), num/den via shfl_xor(32),
//             direct coalesced stores.
// ws floats: Yf 2097152 | Xf 2097152 | Wf 98304 | pk 2097152 |
//            c 131072 | cd 131072 | tot 262144 | off 262144   (~28.7 MB)

typedef __attribute__((ext_vector_type(8))) short short8;  // 8 bf16
typedef __attribute__((ext_vector_type(4))) float f32x4;

__device__ __forceinline__ float phi_f(float x) {
    return x > 0.f ? x + 1.f : __expf(x);   // elu(x)+1
}
__device__ __forceinline__ unsigned short f2bf(float x) {
    __hip_bfloat16 h = __float2bfloat16(x);   // RNE
    return *reinterpret_cast<unsigned short*>(&h);
}
__device__ __forceinline__ float bf2f(unsigned short u) {
    return __uint_as_float(((unsigned int)u) << 16);
}

// ---------------- K1: convert + permute to fragment order -----------------
// grid 1027: blocks 0..511 -> Y, 512..1023 -> X, 1024..1026 -> Wq/Wv/Wk.
// chunk cc -> (ln=cc&15, qd=(cc>>4)&3, kt=(cc>>6)&7, tile=cc>>9);
// src elems (row=tile*16+ln, k=kt*32+qd*8 .. +7); dst = 8*cc.
__global__ __launch_bounds__(256) void k_prep(
        const float* __restrict__ Y, const float* __restrict__ X,
        const float* __restrict__ Wq, const float* __restrict__ Wk,
        const float* __restrict__ Wv,
        unsigned short* __restrict__ Yf, unsigned short* __restrict__ Xf,
        unsigned short* __restrict__ Wf)
{
    const int bx = blockIdx.x, t = threadIdx.x;
    if (bx < 1024) {
        const float* src = (bx < 512) ? Y : X;
        unsigned short* dst = (bx < 512) ? Yf : Xf;
        const int b = bx & 511;
#pragma unroll
        for (int it = 0; it < 4; ++it) {
            const int cc = b * 1024 + it * 256 + t;
            const int ln = cc & 15, qd = (cc >> 4) & 3, kt = (cc >> 6) & 7, rt = cc >> 9;
            const float* s = src + (size_t)(rt * 16 + ln) * 256 + kt * 32 + qd * 8;
            float4 f0 = *(const float4*)s, f1 = *(const float4*)(s + 4);
            short8 o;
            o[0] = f2bf(f0.x); o[1] = f2bf(f0.y); o[2] = f2bf(f0.z); o[3] = f2bf(f0.w);
            o[4] = f2bf(f1.x); o[5] = f2bf(f1.y); o[6] = f2bf(f1.z); o[7] = f2bf(f1.w);
            *(short8*)(dst + (size_t)cc * 8) = o;
        }
    } else {
        const int mat = bx - 1024;                      // 0=q, 1=v, 2=k
        const float* src = (mat == 0) ? Wq : (mat == 1 ? Wv : Wk);
#pragma unroll 4
        for (int it = 0; it < 32; ++it) {
            const int cc = it * 256 + t;
            const int ln = cc & 15, qd = (cc >> 4) & 3, kt = (cc >> 6) & 7, jt = cc >> 9;
            const float* s = src + (size_t)(jt * 16 + ln) * 256 + kt * 32 + qd * 8;
            float4 f0 = *(const float4*)s, f1 = *(const float4*)(s + 4);
            short8 o;
            o[0] = f2bf(f0.x); o[1] = f2bf(f0.y); o[2] = f2bf(f0.z); o[3] = f2bf(f0.w);
            o[4] = f2bf(f1.x); o[5] = f2bf(f1.y); o[6] = f2bf(f1.z); o[7] = f2bf(f1.w);
            *(short8*)(Wf + (size_t)(mat * 8192 + cc) * 8) = o;
        }
    }
}

// ---------------- K2: register-resident fused GEMM ------------------------
// grid 512 (32 rows each), block 256 (4 waves; wave w = cols w*64..+63
// = heads 2w, 2w+1). No barriers in the k-loop.
__global__ __launch_bounds__(256, 2) void k_gemm(
        const unsigned short* __restrict__ Yf, const unsigned short* __restrict__ Xf,
        const unsigned short* __restrict__ Wf,
        unsigned short* __restrict__ pk_out,
        float* __restrict__ c_out, float* __restrict__ cd_out,
        float* __restrict__ tot)
{
    __shared__ float scc[32][8], scd[32][8];
    __shared__ __align__(16) unsigned short spk[32 * 264];

    const int rb = blockIdx.x;            // rows 32rb..32rb+31
    const int n = rb >> 8;
    const int tile = rb & 255;            // 32-row tile index within segment
    const int lseg0 = tile * 32;
    const bool hasprev = (tile != 0);
    const int t = threadIdx.x, w = t >> 6, lane = t & 63;
    const int ln = lane & 15, qd = lane >> 4;

    const short8* Y8 = (const short8*)Yf;
    const short8* X8 = (const short8*)Xf;
    const short8* W8 = (const short8*)Wf;

    const int rt0 = rb * 2;
    const int rtp = hasprev ? rt0 - 1 : 0;        // clamped; result unused at seg start
    const int fl = qd * 16 + ln;                  // lane index within a fragment

    f32x4 aq[2][4], av[2][4], ak[2][4], aqp[4];
#pragma unroll
    for (int i = 0; i < 2; ++i)
#pragma unroll
        for (int j = 0; j < 4; ++j) {
            aq[i][j] = (f32x4){0.f, 0.f, 0.f, 0.f};
            av[i][j] = (f32x4){0.f, 0.f, 0.f, 0.f};
            ak[i][j] = (f32x4){0.f, 0.f, 0.f, 0.f};
        }
#pragma unroll
    for (int j = 0; j < 4; ++j) aqp[j] = (f32x4){0.f, 0.f, 0.f, 0.f};

#pragma unroll 2
    for (int kt = 0; kt < 8; ++kt) {
        short8 ayp = Y8[(size_t)((rtp * 8 + kt) * 4) * 16 + fl];
        short8 ay0 = Y8[(size_t)((rt0 * 8 + kt) * 4) * 16 + fl];
        short8 ay1 = Y8[(size_t)(((rt0 + 1) * 8 + kt) * 4) * 16 + fl];
        short8 ax0 = X8[(size_t)((rt0 * 8 + kt) * 4) * 16 + fl];
        short8 ax1 = X8[(size_t)(((rt0 + 1) * 8 + kt) * 4) * 16 + fl];
#pragma unroll
        for (int j = 0; j < 4; ++j) {          // q (mat 0) + boundary tile
            short8 b = W8[(size_t)(((0 * 16 + w * 4 + j) * 8 + kt) * 4) * 16 + fl];
            aqp[j]   = __builtin_amdgcn_mfma_f32_16x16x32_bf16(ayp, b, aqp[j], 0, 0, 0);
            aq[0][j] = __builtin_amdgcn_mfma_f32_16x16x32_bf16(ay0, b, aq[0][j], 0, 0, 0);
            aq[1][j] = __builtin_amdgcn_mfma_f32_16x16x32_bf16(ay1, b, aq[1][j], 0, 0, 0);
        }
#pragma unroll
        for (int j = 0; j < 4; ++j) {          // v (mat 1)
            short8 b = W8[(size_t)(((1 * 16 + w * 4 + j) * 8 + kt) * 4) * 16 + fl];
            av[0][j] = __builtin_amdgcn_mfma_f32_16x16x32_bf16(ax0, b, av[0][j], 0, 0, 0);
            av[1][j] = __builtin_amdgcn_mfma_f32_16x16x32_bf16(ax1, b, av[1][j], 0, 0, 0);
        }
#pragma unroll
        for (int j = 0; j < 4; ++j) {          // k (mat 2)
            short8 b = W8[(size_t)(((2 * 16 + w * 4 + j) * 8 + kt) * 4) * 16 + fl];
            ak[0][j] = __builtin_amdgcn_mfma_f32_16x16x32_bf16(ax0, b, ak[0][j], 0, 0, 0);
            ak[1][j] = __builtin_amdgcn_mfma_f32_16x16x32_bf16(ax1, b, ak[1][j], 0, 0, 0);
        }
    }

    // phi on q
#pragma unroll
    for (int i = 0; i < 2; ++i)
#pragma unroll
        for (int j = 0; j < 4; ++j)
#pragma unroll
            for (int r = 0; r < 4; ++r) aq[i][j][r] = phi_f(aq[i][j][r]);

    // boundary pq[mbase-1] per (j, ln): row 15 of prev tile lives at lane 48+ln
    float pprev[4];
#pragma unroll
    for (int j = 0; j < 4; ++j) {
        float p15 = __shfl(aqp[j][3], 48 + ln);
        pprev[j] = hasprev ? phi_f(p15) : 0.f;
    }

    // c, cden per (row, head): dpq chain via shuffles
    float cc_[2][2][4], cd_[2][2][4];
#pragma unroll
    for (int i = 0; i < 2; ++i)
#pragma unroll
        for (int jh = 0; jh < 2; ++jh)
#pragma unroll
            for (int r = 0; r < 4; ++r) { cc_[i][jh][r] = 0.f; cd_[i][jh][r] = 0.f; }
#pragma unroll
    for (int j = 0; j < 4; ++j) {
        const int jh = j >> 1;
        float carry = pprev[j];
#pragma unroll
        for (int i = 0; i < 2; ++i) {
            const float p0 = aq[i][j][0], p1 = aq[i][j][1], p2 = aq[i][j][2], p3 = aq[i][j][3];
            const float up3 = __shfl_up(p3, 16);
            const float prev0 = (qd == 0) ? carry : up3;
            const float d0 = p0 - prev0, d1 = p1 - p0, d2 = p2 - p1, d3 = p3 - p2;
            cc_[i][jh][0] += d0 * av[i][j][0]; cd_[i][jh][0] += d0;
            cc_[i][jh][1] += d1 * av[i][j][1]; cd_[i][jh][1] += d1;
            cc_[i][jh][2] += d2 * av[i][j][2]; cd_[i][jh][2] += d2;
            cc_[i][jh][3] += d3 * av[i][j][3]; cd_[i][jh][3] += d3;
            carry = __shfl(p3, ln + 48);
        }
    }
#pragma unroll
    for (int i = 0; i < 2; ++i)
#pragma unroll
        for (int jh = 0; jh < 2; ++jh)
#pragma unroll
            for (int r = 0; r < 4; ++r) {
                float x = cc_[i][jh][r];
                x += __shfl_xor(x, 1); x += __shfl_xor(x, 2);
                x += __shfl_xor(x, 4); x += __shfl_xor(x, 8);
                float y = cd_[i][jh][r];
                y += __shfl_xor(y, 1); y += __shfl_xor(y, 2);
                y += __shfl_xor(y, 4); y += __shfl_xor(y, 8);
                if (ln == 0) {
                    scc[i * 16 + qd * 4 + r][2 * w + jh] = x;
                    scd[i * 16 + qd * 4 + r][2 * w + jh] = y;
                }
            }
    __syncthreads();
    {
        const int row = t & 31, h = t >> 5;
        const size_t gi = (size_t)(n * 8 + h) * 8192 + lseg0 + row;
        c_out[gi]  = scc[row][h];
        cd_out[gi] = scd[row][h];
    }

    // phi on k
#pragma unroll
    for (int i = 0; i < 2; ++i)
#pragma unroll
        for (int j = 0; j < 4; ++j)
#pragma unroll
            for (int r = 0; r < 4; ++r) ak[i][j][r] = phi_f(ak[i][j][r]);

    // 32-row tile totals per (head, d, num/den)
#pragma unroll
    for (int j = 0; j < 4; ++j) {
        const int head = 2 * w + (j >> 1);
        float tn = 0.f, td = 0.f;
#pragma unroll
        for (int i = 0; i < 2; ++i)
#pragma unroll
            for (int r = 0; r < 4; ++r) {
                const int row = i * 16 + qd * 4 + r;
                const float pv = ak[i][j][r];
                tn += scc[row][head] * pv;
                td += scd[row][head] * pv;
            }
        tn += __shfl_xor(tn, 16); tn += __shfl_xor(tn, 32);
        td += __shfl_xor(td, 16); td += __shfl_xor(td, 32);
        if (qd == 0) {
            const int d = (j & 1) * 16 + ln;
            const size_t bi = ((size_t)(n * 8 + head) * 256 + tile) * 64;
            tot[bi + d]      = tn;
            tot[bi + 32 + d] = td;
        }
    }

    // pk -> global bf16 via LDS transpose
#pragma unroll
    for (int i = 0; i < 2; ++i)
#pragma unroll
        for (int j = 0; j < 4; ++j)
#pragma unroll
            for (int r = 0; r < 4; ++r)
                spk[(i * 16 + qd * 4 + r) * 264 + w * 64 + j * 16 + ln] = f2bf(ak[i][j][r]);
    __syncthreads();
#pragma unroll
    for (int it = 0; it < 4; ++it) {
        const int idx = t + 256 * it;     // 1024 chunks (32 rows x 32 col-groups)
        const int row = idx >> 5, cg = idx & 31;
        short8 vals = *(const short8*)&spk[row * 264 + cg * 8];
        const int head = cg >> 2, d8 = (cg & 3) * 8;
        *(short8*)(pk_out + ((size_t)(n * 8 + head) * 8192 + lseg0 + row) * 32 + d8) = vals;
    }
}

// ---------------- K3: exclusive prefix over 256 tile-totals / seg ---------
__global__ __launch_bounds__(256) void k_off(
        const float* __restrict__ tot, float* __restrict__ offs)
{
    __shared__ float wsum[4][64];
    const int seg = blockIdx.x, t = threadIdx.x;
    const int wv = t >> 6, lane = t & 63;
    float s = 0.f;
#pragma unroll 8
    for (int ch = 0; ch < 64; ++ch)
        s += tot[((size_t)seg * 256 + wv * 64 + ch) * 64 + lane];
    wsum[wv][lane] = s;
    __syncthreads();
    float run = 0.f;
    for (int j = 0; j < wv; ++j) run += wsum[j][lane];
#pragma unroll 8
    for (int ch = 0; ch < 64; ++ch) {
        const size_t idx = ((size_t)seg * 256 + wv * 64 + ch) * 64 + lane;
        offs[idx] = run;
        run += tot[idx];
    }
}

// ---------------- K4: final scan + divide + store -------------------------
// grid 512 = 16 segs x 32 blocks (256 rows); wave wv owns 64 rows.
__global__ __launch_bounds__(256) void k_scan(
        const unsigned short* __restrict__ pk, const float* __restrict__ c,
        const float* __restrict__ cd, const float* __restrict__ offs,
        float* __restrict__ out)
{
    __shared__ __align__(16) unsigned short spk[256 * 32];  // 16 KB bf16
    __shared__ float sc[256], sd[256];

    const int bx = blockIdx.x, seg = bx >> 5, blk = bx & 31;
    const int n = seg >> 3, h = seg & 7;
    const int t = threadIdx.x, l0 = blk * 256;

#pragma unroll
    for (int i = 0; i < 4; ++i) {
        const int idx = t + 256 * i;      // 1024 short8 chunks; layouts identical
        *(short8*)&spk[idx * 8] = *(const short8*)(pk + ((size_t)seg * 8192 + l0) * 32 + idx * 8);
    }
    sc[t] = c[(size_t)seg * 8192 + l0 + t];
    sd[t] = cd[(size_t)seg * 8192 + l0 + t];
    __syncthreads();

    const int wv = t >> 6, lane = t & 63;
    const int d = lane & 31, part = lane >> 5;
    float run = offs[((size_t)seg * 256 + blk * 8 + wv * 2) * 64 + lane];
    const float* coefs = part ? sd : sc;
    float* obase = out + ((size_t)n * 8192 + l0 + wv * 64) * 256 + h * 32 + d;

#pragma unroll
    for (int p = 0; p < 64; ++p) {
        const int m = wv * 64 + p;
        run += coefs[m] * bf2f(spk[m * 32 + d]);
        const float other = __shfl_xor(run, 32);   // pair num<->den
        if (!part) obase[(size_t)p * 256] = run / other;
    }
}

extern "C" void kernel_launch(void* const* d_in, const int* in_sizes, int n_in,
                              void* d_out, int out_size, void* d_ws, size_t ws_size,
                              hipStream_t stream)
{
    const float* Y  = (const float*)d_in[0];
    const float* X  = (const float*)d_in[1];
    const float* Wq = (const float*)d_in[2];
    const float* Wk = (const float*)d_in[3];
    const float* Wv = (const float*)d_in[4];
    float* out = (float*)d_out;

    float* ws = (float*)d_ws;
    unsigned short* Yf = (unsigned short*)ws;                    // 4194304 bf16
    unsigned short* Xf = (unsigned short*)(ws + 2097152);        // 4194304 bf16
    unsigned short* Wf = (unsigned short*)(ws + 4194304);        // 196608 bf16
    unsigned short* pk = (unsigned short*)(ws + 4292608);        // 4194304 bf16
    float* c   = ws + 6389760;
    float* cd  = c  + 131072;
    float* tot = cd + 131072;    // 16*256*64
    float* off = tot + 262144;

    hipLaunchKernelGGL(k_prep, dim3(1027), dim3(256), 0, stream,
                       Y, X, Wq, Wk, Wv, Yf, Xf, Wf);
    hipLaunchKernelGGL(k_gemm, dim3(512),  dim3(256), 0, stream,
                       Yf, Xf, Wf, pk, c, cd, tot);
    hipLaunchKernelGGL(k_off,  dim3(16),   dim3(256), 0, stream, tot, off);
    hipLaunchKernelGGL(k_scan, dim3(512),  dim3(256), 0, stream, pk, c, cd, off, out);
}